// Round 8
// baseline (476.353 us; speedup 1.0000x reference)
//
#include <hip/hip_runtime.h>
#include <hip/hip_bf16.h>

typedef float f32x4 __attribute__((ext_vector_type(4)));
typedef short short8 __attribute__((ext_vector_type(8)));
typedef unsigned int uint2v __attribute__((ext_vector_type(2)));

#define DI __device__ __forceinline__

DI unsigned short f2bf(float f) {
  unsigned int u = __float_as_uint(f);
  u += 0x7fffu + ((u >> 16) & 1u);
  return (unsigned short)(u >> 16);
}

DI unsigned int packbf(float a, float b) {
  return (unsigned int)f2bf(a) | ((unsigned int)f2bf(b) << 16);
}

DI void gload16(const unsigned short* g, unsigned short* l) {
  __builtin_amdgcn_global_load_lds((const __attribute__((address_space(1))) void*)g,
                                   (__attribute__((address_space(3))) void*)l, 16, 0, 0);
}

// ---------------- elementwise f32 -> bf16 ----------------
__global__ void cvt_bf16_kernel(const float* __restrict__ src,
                                unsigned short* __restrict__ dst, long n) {
  long i = ((long)blockIdx.x * blockDim.x + threadIdx.x) * 8;
  if (i >= n) return;
  float4 a = *(const float4*)(src + i);
  float4 b = *(const float4*)(src + i + 4);
  short8 v;
  v[0] = f2bf(a.x); v[1] = f2bf(a.y); v[2] = f2bf(a.z); v[3] = f2bf(a.w);
  v[4] = f2bf(b.x); v[5] = f2bf(b.y); v[6] = f2bf(b.z); v[7] = f2bf(b.w);
  *(short8*)(dst + i) = v;
}

// ---------------- tiled transpose + convert (f32 [R][C] -> bf16 [C][R]) ----------------
__global__ void transpose_cvt_kernel(const float* __restrict__ src,
                                     unsigned short* __restrict__ dst,
                                     int ldsrc, int lddst, long sBatch, long dBatch) {
  __shared__ float tile[32][33];
  const float* s = src + (long)blockIdx.z * sBatch;
  unsigned short* d = dst + (long)blockIdx.z * dBatch;
  int c0 = blockIdx.x * 32, r0 = blockIdx.y * 32;
  int tx = threadIdx.x, ty = threadIdx.y;
#pragma unroll
  for (int k = 0; k < 4; k++)
    tile[ty + 8 * k][tx] = s[(long)(r0 + ty + 8 * k) * ldsrc + c0 + tx];
  __syncthreads();
#pragma unroll
  for (int k = 0; k < 4; k++)
    d[(long)(c0 + ty + 8 * k) * lddst + r0 + tx] = f2bf(tile[tx][ty + 8 * k]);
}

// ---------------- V transpose into blocked, granule-swizzled layout ----------------
// src: qkv [b][2048 s][2560], cols 2304..2559 = V[s][256 d]
// dst: VtC [b][kc=s>>5][256 d][32 kw], element kw stored at kw ^ ((d&3)<<3)
__global__ void transpose_v_kernel(const float* __restrict__ qkv,
                                   unsigned short* __restrict__ VtC) {
  __shared__ float tile[32][33];
  int b = blockIdx.z;
  int d0 = blockIdx.x * 32, s0 = blockIdx.y * 32;
  int tx = threadIdx.x, ty = threadIdx.y;
  const float* s = qkv + (long)b * 2048 * 2560 + 2304;
#pragma unroll
  for (int k = 0; k < 4; k++)
    tile[ty + 8 * k][tx] = s[(long)(s0 + ty + 8 * k) * 2560 + d0 + tx];
  __syncthreads();
  unsigned short* d = VtC + (long)b * 524288 + (long)(s0 >> 5) * 8192;
#pragma unroll
  for (int k = 0; k < 4; k++) {
    int dd = d0 + ty + 8 * k;
    d[dd * 32 + (tx ^ ((dd & 3) << 3))] = f2bf(tile[tx][ty + 8 * k]);
  }
}

// ---------------- RoPE: qkv f32 -> Q bf16 [bh][s][256] (linear), K bf16 swizzled ----------------
// Ksw element d stored at d ^ ((s&7)<<3)  (granule pre-swizzle for LDS staging)
__global__ void rope_kernel(const float* __restrict__ qkv, const float* __restrict__ cs,
                            const float* __restrict__ sn, unsigned short* __restrict__ Qb,
                            unsigned short* __restrict__ Ksw) {
  int bid = blockIdx.x;
  int hp = bid % 9;        // 0..7 = Q heads, 8 = K
  int bs = bid / 9;        // b*2048 + s
  int d = threadIdx.x;     // 0..255
  long row = (long)bs * 2560 + hp * 256;
  float x = qkv[row + d];
  float o = (d < 128) ? -qkv[row + d + 128] : qkv[row + d - 128];
  long ci = (long)bs * 256 + d;
  float r = x * cs[ci] + o * sn[ci];
  unsigned short v = f2bf(r);
  if (hp < 8) {
    int b = bs >> 11, s = bs & 2047;
    Qb[((long)(b * 8 + hp) * 2048 + s) * 256 + d] = v;
  } else {
    Ksw[(long)bs * 256 + (d ^ ((bs & 7) << 3))] = v;
  }
}

// ---------------- generic 128x128 MFMA GEMM: C = A @ Bt^T ----------------
template <bool AF32, bool CBF16>
__launch_bounds__(256)
__global__ void gemm_bt_kernel(const void* __restrict__ Av,
                               const unsigned short* __restrict__ Btg,
                               void* __restrict__ Cv,
                               int K, int lda, int ldb, int ldc,
                               int zShift, long aBatch, long bBatch, long cBatch, long cHead) {
  __shared__ unsigned short Asm_[128 * 32];
  __shared__ unsigned short Bsm_[128 * 32];
  int z = blockIdx.z;
  int zb = z >> zShift, zh = z - (zb << zShift);
  const unsigned short* Bt = Btg + (long)zb * bBatch;
  const unsigned short* A16 = (const unsigned short*)Av + (long)z * aBatch;
  const float* A32 = (const float*)Av + (long)z * aBatch;
  int m0 = blockIdx.y * 128, n0 = blockIdx.x * 128;
  int tid = threadIdx.x, w = tid >> 6, lane = tid & 63, c = lane & 15, t = lane >> 4;
  int wm = w >> 1, wn = w & 1;
  f32x4 zero4 = {0.f, 0.f, 0.f, 0.f};
  f32x4 acc[4][4];
#pragma unroll
  for (int i = 0; i < 4; i++)
#pragma unroll
    for (int j = 0; j < 4; j++) acc[i][j] = zero4;

  for (int kt = 0; kt < K; kt += 32) {
    if constexpr (!AF32) {
#pragma unroll
      for (int jj = 0; jj < 2; jj++) {
        int slot = (w * 2 + jj) * 64 + lane;
        int r = slot >> 2, g = slot & 3;
        int gs = g ^ ((r >> 1) & 3);
        gload16(A16 + (long)(m0 + r) * lda + kt + gs * 8, Asm_ + slot * 8);
      }
    } else {
#pragma unroll
      for (int jj = 0; jj < 2; jj++) {
        int slot = jj * 256 + tid;
        int r = slot >> 2, g = slot & 3;
        int gs = g ^ ((r >> 1) & 3);
        const float* p = A32 + (long)(m0 + r) * lda + kt + gs * 8;
        float4 x = *(const float4*)p;
        float4 y = *(const float4*)(p + 4);
        short8 v;
        v[0] = f2bf(x.x); v[1] = f2bf(x.y); v[2] = f2bf(x.z); v[3] = f2bf(x.w);
        v[4] = f2bf(y.x); v[5] = f2bf(y.y); v[6] = f2bf(y.z); v[7] = f2bf(y.w);
        *(short8*)(Asm_ + slot * 8) = v;
      }
    }
#pragma unroll
    for (int jj = 0; jj < 2; jj++) {
      int slot = (w * 2 + jj) * 64 + lane;
      int r = slot >> 2, g = slot & 3;
      int gs = g ^ ((r >> 1) & 3);
      gload16(Bt + (long)(n0 + r) * ldb + kt + gs * 8, Bsm_ + slot * 8);
    }
    __syncthreads();
    short8 af[4], bfg[4];
#pragma unroll
    for (int mi = 0; mi < 4; mi++) {
      int r = wm * 64 + mi * 16 + c;
      af[mi] = *(const short8*)(Asm_ + r * 32 + ((t ^ ((r >> 1) & 3)) * 8));
    }
#pragma unroll
    for (int ni = 0; ni < 4; ni++) {
      int r = wn * 64 + ni * 16 + c;
      bfg[ni] = *(const short8*)(Bsm_ + r * 32 + ((t ^ ((r >> 1) & 3)) * 8));
    }
#pragma unroll
    for (int mi = 0; mi < 4; mi++)
#pragma unroll
      for (int ni = 0; ni < 4; ni++)
        acc[mi][ni] = __builtin_amdgcn_mfma_f32_16x16x32_bf16(af[mi], bfg[ni], acc[mi][ni], 0, 0, 0);
    __syncthreads();
  }
  long cOff = (long)zb * cBatch + zh * cHead;
#pragma unroll
  for (int mi = 0; mi < 4; mi++) {
#pragma unroll
    for (int j = 0; j < 4; j++) {
      int row = m0 + wm * 64 + mi * 16 + t * 4 + j;
#pragma unroll
      for (int ni = 0; ni < 4; ni++) {
        int col = n0 + wn * 64 + ni * 16 + c;
        float v = acc[mi][ni][j];
        long idx = cOff + (long)row * ldc + col;
        if constexpr (CBF16) ((unsigned short*)Cv)[idx] = f2bf(v);
        else ((float*)Cv)[idx] = v;
      }
    }
  }
}

// ---------------- fused attention: QK^T + softmax + attnW store + PV ----------------
// 1D grid 512 (XCD-swizzled): 64 q-rows per block, 2 waves x 32 q (2 q-tiles each).
// K/V LDS fragment reads are shared across both q-tiles of a wave -> half the
// LDS-pipe pressure per q vs 16q/wave. LDS 68KB -> 2 blocks/CU.
// Constant-shift softmax: weight = exp(s) / sum_k exp(s)  (shift cancels exactly)
#define KC 32
__launch_bounds__(128, 2)
__global__ void attn_fused_kernel(const unsigned short* __restrict__ Qb,
                                  const unsigned short* __restrict__ Ksw,
                                  const unsigned short* __restrict__ VtC,
                                  const float* __restrict__ mask,
                                  float* __restrict__ attnW,
                                  unsigned short* __restrict__ attnO) {
  __shared__ unsigned short Ksm[2][KC * 256];   // 2 x 16KB
  __shared__ unsigned short Vsm[2][256 * KC];   // 2 x 16KB
  __shared__ unsigned short Pw[2][2][16 * 32];  // [wave][qtile] 4 x 1KB
  // bijective XCD swizzle (512 % 8 == 0)
  const int id = blockIdx.x;
  const int sw = (id & 7) * 64 + (id >> 3);
  const int qblk = sw & 31, bh = sw >> 5;
  const int b = bh >> 3;
  const int tid = threadIdx.x, w = tid >> 6, lane = tid & 63;
  const int c = lane & 15, t = lane >> 4;
  const int q0 = qblk * 64 + w * 32;   // wave's 32 q rows
  const float scale = 0.0625f;

  // Q fragments for both q-tiles (B-operand: col=c -> q0 + u*16 + c)
  short8 qf0[8], qf1[8];
  {
    const unsigned short* Qr0 = Qb + ((long)bh * 2048 + q0 + c) * 256 + t * 8;
    const unsigned short* Qr1 = Qr0 + 16 * 256;
#pragma unroll
    for (int ks = 0; ks < 8; ks++) {
      qf0[ks] = *(const short8*)(Qr0 + ks * 32);
      qf1[ks] = *(const short8*)(Qr1 + ks * 32);
    }
  }

  const unsigned short* Kg = Ksw + (long)b * 524288;
  const float* mrow0 = mask + (long)b * 4194304 + (long)(q0 + c) * 2048 + t * 4;
  const float* mrow1 = mrow0 + 16 * 2048;

  float lp0 = 0.f, lp1 = 0.f;

  // ---- pass 1: sum of exp(s) (no max tracking; shift cancels in normalization) ----
#pragma unroll
  for (int i = 0; i < 8; i++) {
    int slot = i * 128 + tid;
    gload16(Kg + slot * 8, Ksm[0] + slot * 8);
  }
  for (int kc = 0; kc < 64; kc++) {
    int cur = kc & 1;
    __syncthreads();  // drains staged loads for buf[cur]; frees buf[cur^1]
    if (kc < 63) {
      const unsigned short* src = Kg + (long)(kc + 1) * 8192;
#pragma unroll
      for (int i = 0; i < 8; i++) {
        int slot = i * 128 + tid;
        gload16(src + slot * 8, Ksm[cur ^ 1] + slot * 8);
      }
    }
    f32x4 a00 = {0.f, 0.f, 0.f, 0.f}, a01 = a00, a10 = a00, a11 = a00;
#pragma unroll
    for (int ks = 0; ks < 8; ks++) {
      int g0 = ((ks * 4 + t) ^ (c & 7)) * 8;
      short8 k0 = *(const short8*)(Ksm[cur] + c * 256 + g0);
      short8 k1 = *(const short8*)(Ksm[cur] + (16 + c) * 256 + g0);
      a00 = __builtin_amdgcn_mfma_f32_16x16x32_bf16(k0, qf0[ks], a00, 0, 0, 0);
      a01 = __builtin_amdgcn_mfma_f32_16x16x32_bf16(k0, qf1[ks], a01, 0, 0, 0);
      a10 = __builtin_amdgcn_mfma_f32_16x16x32_bf16(k1, qf0[ks], a10, 0, 0, 0);
      a11 = __builtin_amdgcn_mfma_f32_16x16x32_bf16(k1, qf1[ks], a11, 0, 0, 0);
    }
    const float* mp0 = mrow0 + kc * 32;
    const float* mp1 = mrow1 + kc * 32;
    f32x4 m00 = *(const f32x4*)(mp0);
    f32x4 m10 = *(const f32x4*)(mp0 + 16);
    f32x4 m01 = *(const f32x4*)(mp1);
    f32x4 m11 = *(const f32x4*)(mp1 + 16);
#pragma unroll
    for (int j = 0; j < 4; j++) {
      lp0 += __expf(a00[j] * scale + m00[j]);
      lp0 += __expf(a10[j] * scale + m10[j]);
      lp1 += __expf(a01[j] * scale + m01[j]);
      lp1 += __expf(a11[j] * scale + m11[j]);
    }
  }
  lp0 += __shfl_xor(lp0, 16); lp0 += __shfl_xor(lp0, 32);
  lp1 += __shfl_xor(lp1, 16); lp1 += __shfl_xor(lp1, 32);
  float ri0 = 1.0f / lp0, ri1 = 1.0f / lp1;

  // ---- pass 2: recompute S, write normalized attnW, accumulate PV ----
  const unsigned short* Vg = VtC + (long)b * 524288;
  float* aW0 = attnW + (long)bh * 4194304 + (long)(q0 + c) * 2048 + t * 4;
  float* aW1 = aW0 + 16 * 2048;
  unsigned short* pw0 = &Pw[w][0][0];
  unsigned short* pw1 = &Pw[w][1][0];
  const int pwbase = c * 32;
  f32x4 accO0[16], accO1[16];
#pragma unroll
  for (int i = 0; i < 16; i++) { accO0[i] = (f32x4){0.f, 0.f, 0.f, 0.f}; accO1[i] = accO0[i]; }

#pragma unroll
  for (int i = 0; i < 8; i++) {
    int slot = i * 128 + tid;
    gload16(Kg + slot * 8, Ksm[0] + slot * 8);
    gload16(Vg + slot * 8, Vsm[0] + slot * 8);
  }
  for (int kc = 0; kc < 64; kc++) {
    int cur = kc & 1;
    __syncthreads();
    if (kc < 63) {
      const unsigned short* ksrc = Kg + (long)(kc + 1) * 8192;
      const unsigned short* vsrc = Vg + (long)(kc + 1) * 8192;
#pragma unroll
      for (int i = 0; i < 8; i++) {
        int slot = i * 128 + tid;
        gload16(ksrc + slot * 8, Ksm[cur ^ 1] + slot * 8);
        gload16(vsrc + slot * 8, Vsm[cur ^ 1] + slot * 8);
      }
    }
    f32x4 a00 = {0.f, 0.f, 0.f, 0.f}, a01 = a00, a10 = a00, a11 = a00;
#pragma unroll
    for (int ks = 0; ks < 8; ks++) {
      int g0 = ((ks * 4 + t) ^ (c & 7)) * 8;
      short8 k0 = *(const short8*)(Ksm[cur] + c * 256 + g0);
      short8 k1 = *(const short8*)(Ksm[cur] + (16 + c) * 256 + g0);
      a00 = __builtin_amdgcn_mfma_f32_16x16x32_bf16(k0, qf0[ks], a00, 0, 0, 0);
      a01 = __builtin_amdgcn_mfma_f32_16x16x32_bf16(k0, qf1[ks], a01, 0, 0, 0);
      a10 = __builtin_amdgcn_mfma_f32_16x16x32_bf16(k1, qf0[ks], a10, 0, 0, 0);
      a11 = __builtin_amdgcn_mfma_f32_16x16x32_bf16(k1, qf1[ks], a11, 0, 0, 0);
    }
    const float* mp0 = mrow0 + kc * 32;
    const float* mp1 = mrow1 + kc * 32;
    f32x4 m00 = *(const f32x4*)(mp0);
    f32x4 m10 = *(const f32x4*)(mp0 + 16);
    f32x4 m01 = *(const f32x4*)(mp1);
    f32x4 m11 = *(const f32x4*)(mp1 + 16);
    f32x4 p00, p10, p01, p11;
#pragma unroll
    for (int j = 0; j < 4; j++) {
      p00[j] = __expf(a00[j] * scale + m00[j]) * ri0;
      p10[j] = __expf(a10[j] * scale + m10[j]) * ri0;
      p01[j] = __expf(a01[j] * scale + m01[j]) * ri1;
      p11[j] = __expf(a11[j] * scale + m11[j]) * ri1;
    }
    // attnW f32 stores (k contiguous per lane thanks to swapped QK^T)
    *(f32x4*)(aW0 + kc * 32) = p00;
    *(f32x4*)(aW0 + kc * 32 + 16) = p10;
    *(f32x4*)(aW1 + kc * 32) = p01;
    *(f32x4*)(aW1 + kc * 32 + 16) = p11;
    // P -> bf16 into wave-private LDS (swizzled by ((c&3)<<3) elements)
    uint2v w00, w10, w01, w11;
    w00[0] = packbf(p00[0], p00[1]); w00[1] = packbf(p00[2], p00[3]);
    w10[0] = packbf(p10[0], p10[1]); w10[1] = packbf(p10[2], p10[3]);
    w01[0] = packbf(p01[0], p01[1]); w01[1] = packbf(p01[2], p01[3]);
    w11[0] = packbf(p11[0], p11[1]); w11[1] = packbf(p11[2], p11[3]);
    *(uint2v*)(pw0 + pwbase + ((t * 4) ^ ((c & 3) << 3))) = w00;
    *(uint2v*)(pw0 + pwbase + ((16 + t * 4) ^ ((c & 3) << 3))) = w10;
    *(uint2v*)(pw1 + pwbase + ((t * 4) ^ ((c & 3) << 3))) = w01;
    *(uint2v*)(pw1 + pwbase + ((16 + t * 4) ^ ((c & 3) << 3))) = w11;
    // PV: A-frag = P (row=c -> q), B-frag = V (col=c -> d); vf shared across q-tiles
    short8 pa0 = *(const short8*)(pw0 + pwbase + ((t * 8) ^ ((c & 3) << 3)));
    short8 pa1 = *(const short8*)(pw1 + pwbase + ((t * 8) ^ ((c & 3) << 3)));
#pragma unroll
    for (int dt = 0; dt < 16; dt++) {
      int d = dt * 16 + c;
      short8 vf = *(const short8*)(Vsm[cur] + d * 32 + ((t * 8) ^ ((c & 3) << 3)));
      accO0[dt] = __builtin_amdgcn_mfma_f32_16x16x32_bf16(pa0, vf, accO0[dt], 0, 0, 0);
      accO1[dt] = __builtin_amdgcn_mfma_f32_16x16x32_bf16(pa1, vf, accO1[dt], 0, 0, 0);
    }
  }
  // attnO epilogue: row = q0 + u*16 + t*4+j, col = h*256 + dt*16 + c
  long ob0 = ((long)b * 2048 + q0 + t * 4) * 2048 + (bh & 7) * 256 + c;
  long ob1 = ob0 + 16 * 2048;
#pragma unroll
  for (int dt = 0; dt < 16; dt++)
#pragma unroll
    for (int j = 0; j < 4; j++) {
      attnO[ob0 + (long)j * 2048 + dt * 16] = f2bf(accO0[dt][j]);
      attnO[ob1 + (long)j * 2048 + dt * 16] = f2bf(accO1[dt][j]);
    }
}

extern "C" void kernel_launch(void* const* d_in, const int* in_sizes, int n_in,
                              void* d_out, int out_size, void* d_ws, size_t ws_size,
                              hipStream_t stream) {
  const float* hidden = (const float*)d_in[0];
  const float* mask = (const float*)d_in[1];
  const float* cosb = (const float*)d_in[2];
  const float* sinb = (const float*)d_in[3];
  const float* Wq = (const float*)d_in[4];
  const float* Wk = (const float*)d_in[5];
  const float* Wv = (const float*)d_in[6];
  const float* Wo = (const float*)d_in[7];
  float* out = (float*)d_out;
  float* attnW = out + 8388608;  // attn_weights [2][8][2048][2048] f32

  char* ws = (char*)d_ws;
  unsigned short* hidB  = (unsigned short*)(ws + 0);          // [4096][2048] bf16
  unsigned short* WqkvT = (unsigned short*)(ws + 16777216);   // [2560][2048] bf16
  unsigned short* WoT   = (unsigned short*)(ws + 27262976);   // [2048][2048] bf16
  float*          qkv   = (float*)(ws + 35651584);            // [4096][2560] f32
  unsigned short* Qb    = (unsigned short*)(ws + 77594624);   // [16][2048][256] bf16
  unsigned short* Ksw   = (unsigned short*)(ws + 94371840);   // [2][2048][256] bf16 (swizzled)
  unsigned short* VtC   = (unsigned short*)(ws + 96468992);   // [2][64][256][32] bf16 (blocked)
  unsigned short* attnO = (unsigned short*)(ws + 98566144);   // [4096][2048] bf16

  // 1) hidden -> bf16
  cvt_bf16_kernel<<<4096, 256, 0, stream>>>(hidden, hidB, 8388608L);
  // 2) pack transposed weights (bf16)
  transpose_cvt_kernel<<<dim3(64, 64, 1), dim3(32, 8), 0, stream>>>(Wq, WqkvT, 2048, 2048, 0, 0);
  transpose_cvt_kernel<<<dim3(8, 64, 1), dim3(32, 8), 0, stream>>>(Wk, WqkvT + (long)2048 * 2048, 256, 2048, 0, 0);
  transpose_cvt_kernel<<<dim3(8, 64, 1), dim3(32, 8), 0, stream>>>(Wv, WqkvT + (long)2304 * 2048, 256, 2048, 0, 0);
  transpose_cvt_kernel<<<dim3(64, 64, 1), dim3(32, 8), 0, stream>>>(Wo, WoT, 2048, 2048, 0, 0);
  // 3) QKV projection: [4096][2560] f32
  gemm_bt_kernel<false, false><<<dim3(20, 32, 1), 256, 0, stream>>>(
      hidB, WqkvT, qkv, 2048, 2048, 2048, 2560, 0, 0, 0, 0, 0);
  // 4) RoPE -> Q bf16 linear, K bf16 swizzled
  rope_kernel<<<36864, 256, 0, stream>>>(qkv, cosb, sinb, Qb, Ksw);
  // 5) V -> blocked transposed bf16
  transpose_v_kernel<<<dim3(8, 64, 2), dim3(32, 8), 0, stream>>>(qkv, VtC);
  // 6) fused attention: attnW (d_out) + attnO  (mask read directly as f32)
  attn_fused_kernel<<<512, 128, 0, stream>>>(Qb, Ksw, VtC, mask, attnW, attnO);
  // 7) output projection -> d_out
  gemm_bt_kernel<false, false><<<dim3(16, 32, 1), 256, 0, stream>>>(
      attnO, WoT, out, 2048, 2048, 2048, 2048, 0, 0, 0, 0, 0);
}

// Round 9
// 389.539 us; speedup vs baseline: 1.2229x; 1.2229x over previous
//
#include <hip/hip_runtime.h>
#include <hip/hip_bf16.h>

typedef float f32x4 __attribute__((ext_vector_type(4)));
typedef short short8 __attribute__((ext_vector_type(8)));
typedef unsigned int uint2v __attribute__((ext_vector_type(2)));

#define DI __device__ __forceinline__

DI unsigned short f2bf(float f) {
  unsigned int u = __float_as_uint(f);
  u += 0x7fffu + ((u >> 16) & 1u);
  return (unsigned short)(u >> 16);
}

DI unsigned int packbf(float a, float b) {
  return (unsigned int)f2bf(a) | ((unsigned int)f2bf(b) << 16);
}

DI void gload16(const unsigned short* g, unsigned short* l) {
  __builtin_amdgcn_global_load_lds((const __attribute__((address_space(1))) void*)g,
                                   (__attribute__((address_space(3))) void*)l, 16, 0, 0);
}

// ---------------- elementwise f32 -> bf16 ----------------
__global__ void cvt_bf16_kernel(const float* __restrict__ src,
                                unsigned short* __restrict__ dst, long n) {
  long i = ((long)blockIdx.x * blockDim.x + threadIdx.x) * 8;
  if (i >= n) return;
  float4 a = *(const float4*)(src + i);
  float4 b = *(const float4*)(src + i + 4);
  short8 v;
  v[0] = f2bf(a.x); v[1] = f2bf(a.y); v[2] = f2bf(a.z); v[3] = f2bf(a.w);
  v[4] = f2bf(b.x); v[5] = f2bf(b.y); v[6] = f2bf(b.z); v[7] = f2bf(b.w);
  *(short8*)(dst + i) = v;
}

// ---------------- tiled transpose + convert (f32 [R][C] -> bf16 [C][R]) ----------------
__global__ void transpose_cvt_kernel(const float* __restrict__ src,
                                     unsigned short* __restrict__ dst,
                                     int ldsrc, int lddst, long sBatch, long dBatch) {
  __shared__ float tile[32][33];
  const float* s = src + (long)blockIdx.z * sBatch;
  unsigned short* d = dst + (long)blockIdx.z * dBatch;
  int c0 = blockIdx.x * 32, r0 = blockIdx.y * 32;
  int tx = threadIdx.x, ty = threadIdx.y;
#pragma unroll
  for (int k = 0; k < 4; k++)
    tile[ty + 8 * k][tx] = s[(long)(r0 + ty + 8 * k) * ldsrc + c0 + tx];
  __syncthreads();
#pragma unroll
  for (int k = 0; k < 4; k++)
    d[(long)(c0 + ty + 8 * k) * lddst + r0 + tx] = f2bf(tile[tx][ty + 8 * k]);
}

// ---------------- V transpose into blocked, granule-swizzled layout ----------------
// src: qkv [b][2048 s][2560], cols 2304..2559 = V[s][256 d]
// dst: VtC [b][kc=s>>5][256 d][32 kw], element kw stored at kw ^ ((d&3)<<3)
__global__ void transpose_v_kernel(const float* __restrict__ qkv,
                                   unsigned short* __restrict__ VtC) {
  __shared__ float tile[32][33];
  int b = blockIdx.z;
  int d0 = blockIdx.x * 32, s0 = blockIdx.y * 32;
  int tx = threadIdx.x, ty = threadIdx.y;
  const float* s = qkv + (long)b * 2048 * 2560 + 2304;
#pragma unroll
  for (int k = 0; k < 4; k++)
    tile[ty + 8 * k][tx] = s[(long)(s0 + ty + 8 * k) * 2560 + d0 + tx];
  __syncthreads();
  unsigned short* d = VtC + (long)b * 524288 + (long)(s0 >> 5) * 8192;
#pragma unroll
  for (int k = 0; k < 4; k++) {
    int dd = d0 + ty + 8 * k;
    d[dd * 32 + (tx ^ ((dd & 3) << 3))] = f2bf(tile[tx][ty + 8 * k]);
  }
}

// ---------------- RoPE: qkv f32 -> Q bf16 [bh][s][256] (linear), K bf16 swizzled ----------------
// Ksw element d stored at d ^ ((s&7)<<3)  (granule pre-swizzle for LDS staging)
__global__ void rope_kernel(const float* __restrict__ qkv, const float* __restrict__ cs,
                            const float* __restrict__ sn, unsigned short* __restrict__ Qb,
                            unsigned short* __restrict__ Ksw) {
  int bid = blockIdx.x;
  int hp = bid % 9;        // 0..7 = Q heads, 8 = K
  int bs = bid / 9;        // b*2048 + s
  int d = threadIdx.x;     // 0..255
  long row = (long)bs * 2560 + hp * 256;
  float x = qkv[row + d];
  float o = (d < 128) ? -qkv[row + d + 128] : qkv[row + d - 128];
  long ci = (long)bs * 256 + d;
  float r = x * cs[ci] + o * sn[ci];
  unsigned short v = f2bf(r);
  if (hp < 8) {
    int b = bs >> 11, s = bs & 2047;
    Qb[((long)(b * 8 + hp) * 2048 + s) * 256 + d] = v;
  } else {
    Ksw[(long)bs * 256 + (d ^ ((bs & 7) << 3))] = v;
  }
}

// ---------------- generic 128x128 MFMA GEMM: C = A @ Bt^T ----------------
template <bool AF32, bool CBF16>
__launch_bounds__(256)
__global__ void gemm_bt_kernel(const void* __restrict__ Av,
                               const unsigned short* __restrict__ Btg,
                               void* __restrict__ Cv,
                               int K, int lda, int ldb, int ldc,
                               int zShift, long aBatch, long bBatch, long cBatch, long cHead) {
  __shared__ unsigned short Asm_[128 * 32];
  __shared__ unsigned short Bsm_[128 * 32];
  int z = blockIdx.z;
  int zb = z >> zShift, zh = z - (zb << zShift);
  const unsigned short* Bt = Btg + (long)zb * bBatch;
  const unsigned short* A16 = (const unsigned short*)Av + (long)z * aBatch;
  const float* A32 = (const float*)Av + (long)z * aBatch;
  int m0 = blockIdx.y * 128, n0 = blockIdx.x * 128;
  int tid = threadIdx.x, w = tid >> 6, lane = tid & 63, c = lane & 15, t = lane >> 4;
  int wm = w >> 1, wn = w & 1;
  f32x4 zero4 = {0.f, 0.f, 0.f, 0.f};
  f32x4 acc[4][4];
#pragma unroll
  for (int i = 0; i < 4; i++)
#pragma unroll
    for (int j = 0; j < 4; j++) acc[i][j] = zero4;

  for (int kt = 0; kt < K; kt += 32) {
    if constexpr (!AF32) {
#pragma unroll
      for (int jj = 0; jj < 2; jj++) {
        int slot = (w * 2 + jj) * 64 + lane;
        int r = slot >> 2, g = slot & 3;
        int gs = g ^ ((r >> 1) & 3);
        gload16(A16 + (long)(m0 + r) * lda + kt + gs * 8, Asm_ + slot * 8);
      }
    } else {
#pragma unroll
      for (int jj = 0; jj < 2; jj++) {
        int slot = jj * 256 + tid;
        int r = slot >> 2, g = slot & 3;
        int gs = g ^ ((r >> 1) & 3);
        const float* p = A32 + (long)(m0 + r) * lda + kt + gs * 8;
        float4 x = *(const float4*)p;
        float4 y = *(const float4*)(p + 4);
        short8 v;
        v[0] = f2bf(x.x); v[1] = f2bf(x.y); v[2] = f2bf(x.z); v[3] = f2bf(x.w);
        v[4] = f2bf(y.x); v[5] = f2bf(y.y); v[6] = f2bf(y.z); v[7] = f2bf(y.w);
        *(short8*)(Asm_ + slot * 8) = v;
      }
    }
#pragma unroll
    for (int jj = 0; jj < 2; jj++) {
      int slot = (w * 2 + jj) * 64 + lane;
      int r = slot >> 2, g = slot & 3;
      int gs = g ^ ((r >> 1) & 3);
      gload16(Bt + (long)(n0 + r) * ldb + kt + gs * 8, Bsm_ + slot * 8);
    }
    __syncthreads();
    short8 af[4], bfg[4];
#pragma unroll
    for (int mi = 0; mi < 4; mi++) {
      int r = wm * 64 + mi * 16 + c;
      af[mi] = *(const short8*)(Asm_ + r * 32 + ((t ^ ((r >> 1) & 3)) * 8));
    }
#pragma unroll
    for (int ni = 0; ni < 4; ni++) {
      int r = wn * 64 + ni * 16 + c;
      bfg[ni] = *(const short8*)(Bsm_ + r * 32 + ((t ^ ((r >> 1) & 3)) * 8));
    }
#pragma unroll
    for (int mi = 0; mi < 4; mi++)
#pragma unroll
      for (int ni = 0; ni < 4; ni++)
        acc[mi][ni] = __builtin_amdgcn_mfma_f32_16x16x32_bf16(af[mi], bfg[ni], acc[mi][ni], 0, 0, 0);
    __syncthreads();
  }
  long cOff = (long)zb * cBatch + zh * cHead;
#pragma unroll
  for (int mi = 0; mi < 4; mi++) {
#pragma unroll
    for (int j = 0; j < 4; j++) {
      int row = m0 + wm * 64 + mi * 16 + t * 4 + j;
#pragma unroll
      for (int ni = 0; ni < 4; ni++) {
        int col = n0 + wn * 64 + ni * 16 + c;
        float v = acc[mi][ni][j];
        long idx = cOff + (long)row * ldc + col;
        if constexpr (CBF16) ((unsigned short*)Cv)[idx] = f2bf(v);
        else ((float*)Cv)[idx] = v;
      }
    }
  }
}

// ---------------- fused attention: QK^T + softmax + attnW store + PV ----------------
// grid 512 (XCD-swizzled), block 512 thr = 8 waves = 4 q-subtiles x 2 roles.
// Role h: QK/exp/attnW on k-rows [16h,16h+16) of each chunk; PV on d-cols
// [128h,128h+128) with FULL k=32 (P tile shared in LDS, mid-chunk raw s_barrier
// that does NOT drain vmcnt -> prefetch stays in flight). 16 waves/CU.
// Constant-shift softmax: weight = exp(s) / sum_k exp(s)  (shift cancels exactly)
#define KC 32
__launch_bounds__(512, 4)
__global__ void attn_fused_kernel(const unsigned short* __restrict__ Qb,
                                  const unsigned short* __restrict__ Ksw,
                                  const unsigned short* __restrict__ VtC,
                                  const float* __restrict__ mask,
                                  float* __restrict__ attnW,
                                  unsigned short* __restrict__ attnO) {
  __shared__ unsigned short Ksm[2][KC * 256];   // 2 x 16KB
  __shared__ unsigned short Vsm[2][256 * KC];   // 2 x 16KB
  __shared__ unsigned short Pt[4][16 * 32];     // per-q-subtile shared P tile, 4KB
  __shared__ float red[8][16];
  // bijective XCD swizzle (512 % 8 == 0)
  const int id = blockIdx.x;
  const int sw = (id & 7) * 64 + (id >> 3);
  const int qblk = sw & 31, bh = sw >> 5;
  const int b = bh >> 3;
  const int tid = threadIdx.x, w = tid >> 6, lane = tid & 63;
  const int c = lane & 15, t = lane >> 4;
  const int s = w & 3, h = w >> 2;
  const int q0 = qblk * 64 + s * 16;   // wave's 16 q rows
  const int kh = 16 * h;               // wave's k-row offset within each chunk
  const float scale = 0.0625f;

  // Q fragments (B-operand: col=c -> q0+c)
  short8 qf[8];
  {
    const unsigned short* Qrow = Qb + ((long)bh * 2048 + q0 + c) * 256 + t * 8;
#pragma unroll
    for (int ks = 0; ks < 8; ks++) qf[ks] = *(const short8*)(Qrow + ks * 32);
  }

  const unsigned short* Kg = Ksw + (long)b * 524288;
  const unsigned short* Vg = VtC + (long)b * 524288;
  const float* mrow = mask + (long)b * 4194304 + (long)(q0 + c) * 2048 + kh + t * 4;

  float lp = 0.f;

  // ---- pass 1: partial sum of exp(s) over this wave's k-half rows ----
#pragma unroll
  for (int i = 0; i < 2; i++) {
    int slot = i * 512 + tid;
    gload16(Kg + slot * 8, Ksm[0] + slot * 8);
  }
  for (int kc = 0; kc < 64; kc++) {
    int cur = kc & 1;
    __syncthreads();  // drains staged loads for buf[cur]; frees buf[cur^1]
    if (kc < 63) {
      const unsigned short* src = Kg + (long)(kc + 1) * 8192;
#pragma unroll
      for (int i = 0; i < 2; i++) {
        int slot = i * 512 + tid;
        gload16(src + slot * 8, Ksm[cur ^ 1] + slot * 8);
      }
    }
    f32x4 mv = *(const f32x4*)(mrow + kc * 32);   // issued before MFMA cluster
    f32x4 a0 = {0.f, 0.f, 0.f, 0.f};
    __builtin_amdgcn_s_setprio(1);
#pragma unroll
    for (int ks = 0; ks < 8; ks++) {
      int g0 = ((ks * 4 + t) ^ (c & 7)) * 8;
      short8 kf = *(const short8*)(Ksm[cur] + (kh + c) * 256 + g0);
      a0 = __builtin_amdgcn_mfma_f32_16x16x32_bf16(kf, qf[ks], a0, 0, 0, 0);
    }
    __builtin_amdgcn_s_setprio(0);
#pragma unroll
    for (int j = 0; j < 4; j++) lp += __expf(a0[j] * scale + mv[j]);
  }
  lp += __shfl_xor(lp, 16);
  lp += __shfl_xor(lp, 32);
  if (t == 0) red[w][c] = lp;
  __syncthreads();
  float rinv = 1.0f / (red[s][c] + red[4 + s][c]);

  // ---- pass 2: recompute S, write normalized attnW, PV over full k with d-half ----
  float* aWrow = attnW + (long)bh * 4194304 + (long)(q0 + c) * 2048 + kh + t * 4;
  unsigned short* myPt = &Pt[s][0];
  const int psw = (c & 3) << 3;
  f32x4 accO[8];
#pragma unroll
  for (int i = 0; i < 8; i++) accO[i] = (f32x4){0.f, 0.f, 0.f, 0.f};

#pragma unroll
  for (int i = 0; i < 2; i++) {
    int slot = i * 512 + tid;
    gload16(Kg + slot * 8, Ksm[0] + slot * 8);
    gload16(Vg + slot * 8, Vsm[0] + slot * 8);
  }
  for (int kc = 0; kc < 64; kc++) {
    int cur = kc & 1;
    __syncthreads();
    if (kc < 63) {
      const unsigned short* ksrc = Kg + (long)(kc + 1) * 8192;
      const unsigned short* vsrc = Vg + (long)(kc + 1) * 8192;
#pragma unroll
      for (int i = 0; i < 2; i++) {
        int slot = i * 512 + tid;
        gload16(ksrc + slot * 8, Ksm[cur ^ 1] + slot * 8);
        gload16(vsrc + slot * 8, Vsm[cur ^ 1] + slot * 8);
      }
    }
    f32x4 mv = *(const f32x4*)(mrow + kc * 32);
    f32x4 a0 = {0.f, 0.f, 0.f, 0.f};
    __builtin_amdgcn_s_setprio(1);
#pragma unroll
    for (int ks = 0; ks < 8; ks++) {
      int g0 = ((ks * 4 + t) ^ (c & 7)) * 8;
      short8 kf = *(const short8*)(Ksm[cur] + (kh + c) * 256 + g0);
      a0 = __builtin_amdgcn_mfma_f32_16x16x32_bf16(kf, qf[ks], a0, 0, 0, 0);
    }
    __builtin_amdgcn_s_setprio(0);
    f32x4 p;
#pragma unroll
    for (int j = 0; j < 4; j++) p[j] = __expf(a0[j] * scale + mv[j]) * rinv;
    // attnW f32 store (col = kc*32 + kh + t*4, k-contiguous per lane)
    *(f32x4*)(aWrow + kc * 32) = p;
    // P -> bf16 into shared q-subtile tile (element k stored at k ^ psw)
    uint2v pw;
    pw[0] = packbf(p[0], p[1]); pw[1] = packbf(p[2], p[3]);
    *(uint2v*)(myPt + c * 32 + ((kh + t * 4) ^ psw)) = pw;
    // mid-chunk barrier: LDS-only sync, vmcnt prefetch stays in flight
    asm volatile("s_waitcnt lgkmcnt(0)" ::: "memory");
    __builtin_amdgcn_s_barrier();
    __builtin_amdgcn_sched_barrier(0);
    // PV: A = full-k P row (q=c), B = V fragment for this wave's d-half
    short8 pa = *(const short8*)(myPt + c * 32 + ((t * 8) ^ psw));
    __builtin_amdgcn_s_setprio(1);
#pragma unroll
    for (int di = 0; di < 8; di++) {
      int d = (8 * h + di) * 16 + c;
      short8 vf = *(const short8*)(Vsm[cur] + d * 32 + ((t * 8) ^ psw));
      accO[di] = __builtin_amdgcn_mfma_f32_16x16x32_bf16(pa, vf, accO[di], 0, 0, 0);
    }
    __builtin_amdgcn_s_setprio(0);
  }
  // attnO epilogue: row = q0 + t*4+j, col = h*128 + di*16 + c (within head)
  long obase = ((long)b * 2048 + q0 + t * 4) * 2048 + (bh & 7) * 256 + h * 128 + c;
#pragma unroll
  for (int di = 0; di < 8; di++)
#pragma unroll
    for (int j = 0; j < 4; j++)
      attnO[obase + (long)j * 2048 + di * 16] = f2bf(accO[di][j]);
}

extern "C" void kernel_launch(void* const* d_in, const int* in_sizes, int n_in,
                              void* d_out, int out_size, void* d_ws, size_t ws_size,
                              hipStream_t stream) {
  const float* hidden = (const float*)d_in[0];
  const float* mask = (const float*)d_in[1];
  const float* cosb = (const float*)d_in[2];
  const float* sinb = (const float*)d_in[3];
  const float* Wq = (const float*)d_in[4];
  const float* Wk = (const float*)d_in[5];
  const float* Wv = (const float*)d_in[6];
  const float* Wo = (const float*)d_in[7];
  float* out = (float*)d_out;
  float* attnW = out + 8388608;  // attn_weights [2][8][2048][2048] f32

  char* ws = (char*)d_ws;
  unsigned short* hidB  = (unsigned short*)(ws + 0);          // [4096][2048] bf16
  unsigned short* WqkvT = (unsigned short*)(ws + 16777216);   // [2560][2048] bf16
  unsigned short* WoT   = (unsigned short*)(ws + 27262976);   // [2048][2048] bf16
  float*          qkv   = (float*)(ws + 35651584);            // [4096][2560] f32
  unsigned short* Qb    = (unsigned short*)(ws + 77594624);   // [16][2048][256] bf16
  unsigned short* Ksw   = (unsigned short*)(ws + 94371840);   // [2][2048][256] bf16 (swizzled)
  unsigned short* VtC   = (unsigned short*)(ws + 96468992);   // [2][64][256][32] bf16 (blocked)
  unsigned short* attnO = (unsigned short*)(ws + 98566144);   // [4096][2048] bf16

  // 1) hidden -> bf16
  cvt_bf16_kernel<<<4096, 256, 0, stream>>>(hidden, hidB, 8388608L);
  // 2) pack transposed weights (bf16)
  transpose_cvt_kernel<<<dim3(64, 64, 1), dim3(32, 8), 0, stream>>>(Wq, WqkvT, 2048, 2048, 0, 0);
  transpose_cvt_kernel<<<dim3(8, 64, 1), dim3(32, 8), 0, stream>>>(Wk, WqkvT + (long)2048 * 2048, 256, 2048, 0, 0);
  transpose_cvt_kernel<<<dim3(8, 64, 1), dim3(32, 8), 0, stream>>>(Wv, WqkvT + (long)2304 * 2048, 256, 2048, 0, 0);
  transpose_cvt_kernel<<<dim3(64, 64, 1), dim3(32, 8), 0, stream>>>(Wo, WoT, 2048, 2048, 0, 0);
  // 3) QKV projection: [4096][2560] f32
  gemm_bt_kernel<false, false><<<dim3(20, 32, 1), 256, 0, stream>>>(
      hidB, WqkvT, qkv, 2048, 2048, 2048, 2560, 0, 0, 0, 0, 0);
  // 4) RoPE -> Q bf16 linear, K bf16 swizzled
  rope_kernel<<<36864, 256, 0, stream>>>(qkv, cosb, sinb, Qb, Ksw);
  // 5) V -> blocked transposed bf16
  transpose_v_kernel<<<dim3(8, 64, 2), dim3(32, 8), 0, stream>>>(qkv, VtC);
  // 6) fused attention: attnW (d_out) + attnO  (mask read directly as f32)
  attn_fused_kernel<<<512, 512, 0, stream>>>(Qb, Ksw, VtC, mask, attnW, attnO);
  // 7) output projection -> d_out
  gemm_bt_kernel<false, false><<<dim3(16, 32, 1), 256, 0, stream>>>(
      attnO, WoT, out, 2048, 2048, 2048, 2048, 0, 0, 0, 0, 0);
}